// Round 17
// baseline (501.400 us; speedup 1.0000x reference)
//
#include <hip/hip_runtime.h>
#include <hip/hip_bf16.h>
#include <math.h>

#define BSZ   128
#define NENT  512
#define NP1   513
#define DENT  256
#define KDIM  128
#define DIN   1024
#define DF    256
#define HDIM  128
#define SSTEP 64
#define G4    512
#define NEGV  (-1e9f)
#define INV_MAX (1.0f/512.0f)

typedef float v2f __attribute__((ext_vector_type(2)));
typedef __attribute__((ext_vector_type(8))) short bf16x8;
typedef __attribute__((ext_vector_type(4))) float f32x4;
typedef long i64;

// ---------------- helpers ----------------
__device__ inline float sigf(float x){ return 1.f/(1.f+__expf(-x)); }
__device__ inline float tanh_fast(float x){ float e=__expf(2.f*x); return 1.f - 2.f/(e+1.f); }

__device__ inline float sum16_partial(float x){
  x += __int_as_float(__builtin_amdgcn_update_dpp(0, __float_as_int(x), 0x111, 0xf, 0xf, true));
  x += __int_as_float(__builtin_amdgcn_update_dpp(0, __float_as_int(x), 0x112, 0xf, 0xf, true));
  x += __int_as_float(__builtin_amdgcn_update_dpp(0, __float_as_int(x), 0x114, 0xf, 0xf, true));
  x += __int_as_float(__builtin_amdgcn_update_dpp(0, __float_as_int(x), 0x118, 0xf, 0xf, true));
  return x;
}
__device__ inline float wave_sum_partial(float x){
  x = sum16_partial(x);
  x += __int_as_float(__builtin_amdgcn_update_dpp(0, __float_as_int(x), 0x142, 0xa, 0xf, true));
  x += __int_as_float(__builtin_amdgcn_update_dpp(0, __float_as_int(x), 0x143, 0xc, 0xf, true));
  return x;
}
__device__ inline float wave_sum(float x){
  return __int_as_float(__builtin_amdgcn_readlane(__float_as_int(wave_sum_partial(x)), 63));
}

__device__ inline unsigned pk8(float4 f){
  int r = 0;
  r = __builtin_amdgcn_cvt_pk_fp8_f32(f.x, f.y, r, false);
  r = __builtin_amdgcn_cvt_pk_fp8_f32(f.z, f.w, r, true);
  return (unsigned)r;
}
__device__ inline i64 u2l(uint2 v){ union{uint2 u; i64 l;} x; x.u=v; return x.l; }

// block = 512 threads (8 waves).
__device__ inline float2 block_reduce2(float x, float y, float* red){
  float sx0 = wave_sum_partial(x), sy0 = wave_sum_partial(y);
  int w = threadIdx.x>>6;
  __syncthreads();
  if((threadIdx.x&63)==63){ red[w]=sx0; red[8+w]=sy0; }
  __syncthreads();
  float sx=0.f, sy=0.f;
  #pragma unroll
  for(int q=0;q<8;q++){ sx+=red[q]; sy+=red[8+q]; }
  return make_float2(sx,sy);
}

// ---------------- generic MFMA GEMM: C[M,N] = act(A[M,K] @ B^T + bias) ----------------
template<bool BKMAJOR, bool RELU, bool GATHER>
__global__ __launch_bounds__(256)
void mfma_gemm(const float* __restrict__ A, const float* __restrict__ B,
               const float* __restrict__ bias, float* __restrict__ C,
               int M, int N, int K,
               const int* __restrict__ gidx, float scale){
  __shared__ ushort Abf[64][72];
  __shared__ ushort Bbf[64][72];
  const int t = threadIdx.x;
  const int bm = blockIdx.x, bn = blockIdx.y;
  const int w = t>>6, l = t&63;
  const int lm = l&15, lg = l>>4;
  const int r0 = w*16;
  f32x4 acc[4];
  #pragma unroll
  for(int f=0;f<4;f++) acc[f] = (f32x4){0.f,0.f,0.f,0.f};

  for(int k0=0;k0<K;k0+=64){
    #pragma unroll
    for(int i=0;i<4;i++){
      int idx = t + i*256;
      int row = idx>>4, c4 = (idx&15)<<2;
      const float* src;
      if(GATHER){
        int gr = bm*64+row;
        src = &A[((size_t)(gr>>6)*NP1 + gidx[gr])*(size_t)K + k0 + c4];
      } else {
        src = &A[((size_t)bm*64+row)*K + k0 + c4];
      }
      float4 v = *(const float4*)src;
      if(GATHER){ v.x*=scale; v.y*=scale; v.z*=scale; v.w*=scale; }
      ushort4 u;
      u.x = __float_as_uint(v.x)>>16; u.y = __float_as_uint(v.y)>>16;
      u.z = __float_as_uint(v.z)>>16; u.w = __float_as_uint(v.w)>>16;
      *(ushort4*)&Abf[row][c4] = u;
    }
    if(!BKMAJOR){
      #pragma unroll
      for(int i=0;i<4;i++){
        int idx = t + i*256;
        int row = idx>>4, c4 = (idx&15)<<2;
        float4 v = *(const float4*)&B[((size_t)bn*64+row)*K + k0 + c4];
        ushort4 u;
        u.x = __float_as_uint(v.x)>>16; u.y = __float_as_uint(v.y)>>16;
        u.z = __float_as_uint(v.z)>>16; u.w = __float_as_uint(v.w)>>16;
        *(ushort4*)&Bbf[row][c4] = u;
      }
    } else {
      #pragma unroll
      for(int i=0;i<4;i++){
        int idx = t + i*256;
        int kr = idx>>4, n4 = (idx&15)<<2;
        float4 v = *(const float4*)&B[(size_t)(k0+kr)*N + bn*64 + n4];
        Bbf[n4+0][kr] = __float_as_uint(v.x)>>16;
        Bbf[n4+1][kr] = __float_as_uint(v.y)>>16;
        Bbf[n4+2][kr] = __float_as_uint(v.z)>>16;
        Bbf[n4+3][kr] = __float_as_uint(v.w)>>16;
      }
    }
    __syncthreads();
    #pragma unroll
    for(int kk=0;kk<64;kk+=32){
      bf16x8 a = *(const bf16x8*)&Abf[r0+lm][kk + lg*8];
      #pragma unroll
      for(int f=0;f<4;f++){
        bf16x8 b = *(const bf16x8*)&Bbf[f*16+lm][kk + lg*8];
        acc[f] = __builtin_amdgcn_mfma_f32_16x16x32_bf16(a, b, acc[f], 0,0,0);
      }
    }
    __syncthreads();
  }
  #pragma unroll
  for(int f=0;f<4;f++){
    int gcol = bn*64 + f*16 + lm;
    float bb = bias ? bias[gcol] : 0.f;
    #pragma unroll
    for(int r=0;r<4;r++){
      int grow = bm*64 + r0 + lg*4 + r;
      float v = acc[f][r] + bb;
      if(RELU) v = fmaxf(v, 0.f);
      C[(size_t)grow*N + gcol] = v;
    }
  }
}

// ---------------- MFMA key GEMM: key = ent @ key_w^T + key_b, end-row folded in -------
__global__ __launch_bounds__(256)
void key_gemm_mfma(const float* __restrict__ A, const float* __restrict__ W,
                   const float* __restrict__ bias, const int* __restrict__ en,
                   const float* __restrict__ end_emb, float* __restrict__ C){
  __shared__ ushort Abf[64][264];
  __shared__ ushort Bbf[128][264];
  __shared__ float bs[128];
  const int t = threadIdx.x;
  const int bm = blockIdx.x;
  #pragma unroll
  for(int i=0;i<16;i++){
    int idx = t + i*256;
    int row = idx>>6, c4 = (idx&63)<<2;
    float4 v = *(const float4*)&A[((size_t)bm*64+row)*256 + c4];
    ushort4 u;
    u.x = __float_as_uint(v.x)>>16; u.y = __float_as_uint(v.y)>>16;
    u.z = __float_as_uint(v.z)>>16; u.w = __float_as_uint(v.w)>>16;
    *(ushort4*)&Abf[row][c4] = u;
  }
  #pragma unroll
  for(int i=0;i<32;i++){
    int idx = t + i*256;
    int row = idx>>6, c4 = (idx&63)<<2;
    float4 v = *(const float4*)&W[(size_t)row*256 + c4];
    ushort4 u;
    u.x = __float_as_uint(v.x)>>16; u.y = __float_as_uint(v.y)>>16;
    u.z = __float_as_uint(v.z)>>16; u.w = __float_as_uint(v.w)>>16;
    *(ushort4*)&Bbf[row][c4] = u;
  }
  if(t<128) bs[t] = bias[t];
  __syncthreads();
  const int w = t>>6, l = t&63;
  const int lm = l&15, lg = l>>4;
  const int r0 = w*16;
  f32x4 acc[8];
  #pragma unroll
  for(int f=0;f<8;f++) acc[f] = (f32x4){0.f,0.f,0.f,0.f};
  #pragma unroll
  for(int k0=0;k0<256;k0+=32){
    bf16x8 a = *(const bf16x8*)&Abf[r0+lm][k0 + lg*8];
    #pragma unroll
    for(int f=0;f<8;f++){
      bf16x8 b = *(const bf16x8*)&Bbf[f*16+lm][k0 + lg*8];
      acc[f] = __builtin_amdgcn_mfma_f32_16x16x32_bf16(a, b, acc[f], 0,0,0);
    }
  }
  #pragma unroll
  for(int f=0;f<8;f++){
    int gcol = f*16 + lm;
    float bb = bs[gcol];
    float ev = end_emb[gcol];
    #pragma unroll
    for(int r=0;r<4;r++){
      int grow = bm*64 + r0 + lg*4 + r;
      int bq = grow>>9, n = grow&511;
      size_t orow = (size_t)bq*NP1 + n;
      float v = acc[f][r] + bb;
      if(n == en[bq]) v = ev;       // end-embedding row (reference .set)
      C[orow*KDIM + gcol] = v;
    }
  }
}

// ---------------- G0 = LN(X @ wih0^T) : 512 blocks x 16 rows, N=512, K=128 ----------------
__global__ __launch_bounds__(256)
void g0_gemm_ln(const float* __restrict__ X, const float* __restrict__ W,
                const float* __restrict__ gam, const float* __restrict__ bet,
                float* __restrict__ G0){
  __shared__ ushort Abf[16][136];
  __shared__ float redS[16][4], redQ[16][4];
  const int t = threadIdx.x, bm = blockIdx.x;
  const int w = t>>6, l = t&63, lm = l&15, lg = l>>4;
  {
    int idx = t*8;
    int row = idx>>7, c = idx&127;
    const float* src = &X[((size_t)bm*16+row)*128 + c];
    float4 a = *(const float4*)src;
    float4 d = *(const float4*)(src+4);
    ushort4 u0, u1;
    u0.x=__float_as_uint(a.x)>>16; u0.y=__float_as_uint(a.y)>>16;
    u0.z=__float_as_uint(a.z)>>16; u0.w=__float_as_uint(a.w)>>16;
    u1.x=__float_as_uint(d.x)>>16; u1.y=__float_as_uint(d.y)>>16;
    u1.z=__float_as_uint(d.z)>>16; u1.w=__float_as_uint(d.w)>>16;
    *(ushort4*)&Abf[row][c] = u0;
    *(ushort4*)&Abf[row][c+4] = u1;
  }
  __syncthreads();
  f32x4 acc[8];
  #pragma unroll
  for(int f=0;f<8;f++) acc[f] = (f32x4){0.f,0.f,0.f,0.f};
  #pragma unroll
  for(int kt=0;kt<4;kt++){
    int k0 = kt*32;
    bf16x8 a = *(const bf16x8*)&Abf[lm][k0 + lg*8];
    #pragma unroll
    for(int f=0;f<8;f++){
      int brow = w*128 + f*16 + lm;
      const float* bp = &W[(size_t)brow*128 + k0 + lg*8];
      float4 b0 = *(const float4*)bp;
      float4 b1 = *(const float4*)(bp+4);
      bf16x8 bfr;
      bfr[0]=(short)(__float_as_uint(b0.x)>>16); bfr[1]=(short)(__float_as_uint(b0.y)>>16);
      bfr[2]=(short)(__float_as_uint(b0.z)>>16); bfr[3]=(short)(__float_as_uint(b0.w)>>16);
      bfr[4]=(short)(__float_as_uint(b1.x)>>16); bfr[5]=(short)(__float_as_uint(b1.y)>>16);
      bfr[6]=(short)(__float_as_uint(b1.z)>>16); bfr[7]=(short)(__float_as_uint(b1.w)>>16);
      acc[f] = __builtin_amdgcn_mfma_f32_16x16x32_bf16(a, bfr, acc[f], 0,0,0);
    }
  }
  float mu[4], rs[4];
  #pragma unroll
  for(int r=0;r<4;r++){
    float s=0.f, q=0.f;
    #pragma unroll
    for(int f=0;f<8;f++){ float x=acc[f][r]; s+=x; q+=x*x; }
    s = sum16_partial(s);
    q = sum16_partial(q);
    if(lm==15){ redS[lg*4+r][w]=s; redQ[lg*4+r][w]=q; }
  }
  __syncthreads();
  #pragma unroll
  for(int r=0;r<4;r++){
    int row = lg*4+r;
    float S = redS[row][0]+redS[row][1]+redS[row][2]+redS[row][3];
    float Q = redQ[row][0]+redQ[row][1]+redQ[row][2]+redQ[row][3];
    mu[r] = S*(1.f/512.f);
    rs[r] = rsqrtf(Q*(1.f/512.f) - mu[r]*mu[r] + 1e-5f);
  }
  #pragma unroll
  for(int f=0;f<8;f++){
    int col = w*128 + f*16 + lm;
    float g = gam[col], bt = bet[col];
    #pragma unroll
    for(int r=0;r<4;r++){
      int grow = bm*16 + lg*4 + r;
      G0[(size_t)grow*G4 + col] = (acc[f][r]-mu[r])*rs[r]*g + bt;
    }
  }
}

// ---------------- c0v[f] = q1_w[f,:] . e2_b ----------------
__global__ __launch_bounds__(256)
void c0_kernel(const float* __restrict__ q1_w, const float* __restrict__ e2_b,
               float* __restrict__ c0v){
  __shared__ float red[4];
  int f = blockIdx.x, t = threadIdx.x;
  float4 a = *(const float4*)&q1_w[(size_t)f*DIN + t*4];
  float4 e = *(const float4*)&e2_b[t*4];
  float p = a.x*e.x + a.y*e.y + a.z*e.z + a.w*e.w;
  float s = wave_sum_partial(p);
  if((t&63)==63) red[t>>6] = s;
  __syncthreads();
  if(t==0) c0v[f] = red[0]+red[1]+red[2]+red[3];
}

// ---------------- gated exclusive prefix over steps; emits relu(U), s1, ng ----------------
__global__ void prefix_kernel(const float* __restrict__ U0, const float* __restrict__ Q1K,
                              const float* __restrict__ c0v, const float* __restrict__ T1,
                              const int* __restrict__ su, const int* __restrict__ en,
                              const int* __restrict__ sun,
                              float* __restrict__ RU, float* __restrict__ s1,
                              float* __restrict__ ngout){
  int b = blockIdx.x, f = threadIdx.x;    // 128 x 256
  float acc = U0[b*DF+f];
  float c0f = c0v[f];
  float s1a = 0.f, ng = 0.f;
  int enb = en[b], sunb = sun[b];
  for(int j=0;j<SSTEP;j++){
    int r = b*SSTEP+j;
    float q = Q1K[(size_t)r*DF+f];
    float tt = T1[(size_t)r*DF+f];
    RU[(size_t)r*DF+f] = fmaxf(acc,0.f);
    int sj = su[r];
    float g = ((j+1)<=sunb && sj!=enb) ? 1.f : 0.f;
    acc = fmaf(g, q + c0f, acc);
    s1a = fmaf(g, tt, s1a);
    ng += g;
  }
  s1[b*DF+f]=s1a;
  if(f==0) ngout[b]=ng;
}

// ---------------- serial 2-layer LN-LSTM scan: MFMA matvecs, 2 barriers/step ----------
// Gates computed REDUNDANTLY on all 8 waves (VALU idle in MFMA regime); h lives in
// wave-private fp8 LDS slots (no barrier on gate->matvec handoff); red/pvv/pv1/pu
// parity double-buffered with disjoint slot ranges so lagging waves never race.
__global__ __launch_bounds__(512)
__attribute__((amdgpu_waves_per_eu(2,2)))
void lstm_serial(const float* __restrict__ wih, const float* __restrict__ whh,
                 const float* __restrict__ G0,
                 const float* __restrict__ ln_ig, const float* __restrict__ ln_ib,
                 const float* __restrict__ ln_hg, const float* __restrict__ ln_hb,
                 const float* __restrict__ ln_cg, const float* __restrict__ ln_cb,
                 float* __restrict__ H1){
  const int b = blockIdx.x;
  const int j = threadIdx.x;
  const int w = j>>6, l = j&63;
  const int lm = l&15, lg = l>>4;
  __shared__ uint2 W0f[4][4][512];     // whh0 fp8 frags [kt][lg][col]  (64 KB)
  __shared__ uint2 W1f[4][4][512];     // wih1 fp8 frags                (64 KB)
  __shared__ uint4 h0own[8][8], h1own[8][8];   // per-wave fp8 h (128 B each, 2 KB)
  __shared__ float pvv[2][512], pv1[2][512], pu[2][512];   // parity dbuf (12 KB)
  __shared__ float lnA[512], lnB[512], lnC[512], lnD[512], lnE[512], lnF[512];
  __shared__ float red[2][48];

  // one-time staging: pack row j of whh0 / wih1 into fragment-major LDS
  {
    unsigned dw[32];
    #pragma unroll
    for(int q=0;q<32;q++) dw[q] = pk8(*(const float4*)&whh[(size_t)j*KDIM + q*4]);
    #pragma unroll
    for(int kt=0;kt<4;kt++)
      #pragma unroll
      for(int g=0;g<4;g++)
        W0f[kt][g][j] = make_uint2(dw[kt*8+g*2], dw[kt*8+g*2+1]);
    #pragma unroll
    for(int q=0;q<32;q++) dw[q] = pk8(*(const float4*)&wih[65536 + (size_t)j*KDIM + q*4]);
    #pragma unroll
    for(int kt=0;kt<4;kt++)
      #pragma unroll
      for(int g=0;g<4;g++)
        W1f[kt][g][j] = make_uint2(dw[kt*8+g*2], dw[kt*8+g*2+1]);
  }
  // whh1 fragments in registers
  uint2 w2f[4][4];
  #pragma unroll
  for(int c=0;c<4;c++){
    int row = w*64 + c*16 + lm;
    #pragma unroll
    for(int kt=0;kt<4;kt++){
      int k0 = kt*32 + lg*8;
      float4 x0 = *(const float4*)&whh[65536 + (size_t)row*KDIM + k0];
      float4 x1 = *(const float4*)&whh[65536 + (size_t)row*KDIM + k0 + 4];
      w2f[c][kt] = make_uint2(pk8(x0), pk8(x1));
    }
  }
  lnA[j] = ln_hg[j];     lnB[j] = ln_hb[j];
  lnC[j] = ln_ig[512+j]; lnD[j] = ln_ib[512+j];
  lnE[j] = ln_hg[512+j]; lnF[j] = ln_hb[512+j];

  // gate state per thread (cells l and l+64), replicated on every wave
  float cg0A=ln_cg[l],     cb0A=ln_cb[l];
  float cg0B=ln_cg[l+64],  cb0B=ln_cb[l+64];
  float cg1A=ln_cg[128+l],    cb1A=ln_cb[128+l];
  float cg1B=ln_cg[128+l+64], cb1B=ln_cb[128+l+64];
  float c0rA=0.f,c0rB=0.f,c1rA=0.f,c1rB=0.f;
  if(l<8){ h0own[w][l]=(uint4){0,0,0,0}; h1own[w][l]=(uint4){0,0,0,0}; }
  __syncthreads();

  const int colbase = w*64;
  int p = 0;

  for(int i=0;i<SSTEP;i++){
    // per-step G0 prefetch (all waves; broadcast addresses)
    float g0a[4], g0b[4];
    {
      const float* gp = &G0[((size_t)b*SSTEP+i)*G4];
      #pragma unroll
      for(int k=0;k<4;k++){ g0a[k]=gp[l+128*k]; g0b[k]=gp[l+64+128*k]; }
    }

    // ---- Phase A: v = whh0@h0own ; v1 = whh1@h1own via MFMA ----
    f32x4 accv[4], acc1[4];
    #pragma unroll
    for(int c=0;c<4;c++){ accv[c]=(f32x4){0.f,0.f,0.f,0.f}; acc1[c]=(f32x4){0.f,0.f,0.f,0.f}; }
    #pragma unroll
    for(int kt=0;kt<4;kt++){
      uint2 a0 = make_uint2(0,0), a1 = make_uint2(0,0);
      if(lm==0){
        a0 = *(const uint2*)((const char*)&h0own[w][0] + kt*32 + lg*8);
        a1 = *(const uint2*)((const char*)&h1own[w][0] + kt*32 + lg*8);
      }
      i64 A0 = u2l(a0), A1 = u2l(a1);
      #pragma unroll
      for(int c=0;c<4;c++){
        accv[c] = __builtin_amdgcn_mfma_f32_16x16x32_fp8_fp8(A0, u2l(W0f[kt][lg][colbase+c*16+lm]), accv[c], 0,0,0);
        acc1[c] = __builtin_amdgcn_mfma_f32_16x16x32_fp8_fp8(A1, u2l(w2f[c][kt]), acc1[c], 0,0,0);
      }
    }
    {
      float sv=0.f, sq=0.f, s1v=0.f, s1q=0.f;
      #pragma unroll
      for(int c=0;c<4;c++){
        float x = accv[c][0]; sv += x; sq += x*x;
        float y = acc1[c][0]; s1v += y; s1q += y*y;
      }
      float a  = wave_sum_partial(sv);
      float bq = wave_sum_partial(sq);
      float c2 = wave_sum_partial(s1v);
      float d  = wave_sum_partial(s1q);
      if(l==63){ red[p][w]=a; red[p][8+w]=bq; red[p][16+w]=c2; red[p][24+w]=d; }
      if(l<16){
        #pragma unroll
        for(int c=0;c<4;c++){
          pvv[p][colbase + c*16 + l] = accv[c][0];
          pv1[p][colbase + c*16 + l] = acc1[c][0];
        }
      }
    }
    __syncthreads();                                      // bar1

    // ---- Phase B: layer-0 gates, REDUNDANT on all waves (cells l, l+64) ----
    {
      float S=0.f,S2=0.f;
      #pragma unroll
      for(int q=0;q<8;q++){ S+=red[p][q]; S2+=red[p][8+q]; }
      float mu = S*(1.f/512.f);
      float rs = rsqrtf(S2*(1.f/512.f) - mu*mu + 1e-5f);
      float ashA[4], ashB[4];
      #pragma unroll
      for(int k=0;k<4;k++){
        int ia = l + 128*k, ib = l + 64 + 128*k;
        ashA[k] = g0a[k] + (pvv[p][ia]-mu)*rs*lnA[ia] + lnB[ia];
        ashB[k] = g0b[k] + (pvv[p][ib]-mu)*rs*lnA[ib] + lnB[ib];
      }
      float cpA = sigf(ashA[1])*c0rA + sigf(ashA[0])*tanh_fast(ashA[2]);
      float cpB = sigf(ashB[1])*c0rB + sigf(ashB[0])*tanh_fast(ashB[2]);
      float s  = wave_sum(cpA+cpB);
      float s2 = wave_sum(cpA*cpA+cpB*cpB);
      float muc = s*(1.f/128.f);
      float rsc = rsqrtf(s2*(1.f/128.f) - muc*muc + 1e-5f);
      c0rA = (cpA-muc)*rsc*cg0A + cb0A;
      c0rB = (cpB-muc)*rsc*cg0B + cb0B;
      float hA = sigf(ashA[3])*tanh_fast(c0rA);
      float hB = sigf(ashB[3])*tanh_fast(c0rB);
      ((unsigned char*)&h0own[w][0])[l]    = (unsigned char)(__builtin_amdgcn_cvt_pk_fp8_f32(hA,hA,0,false)&0xff);
      ((unsigned char*)&h0own[w][0])[l+64] = (unsigned char)(__builtin_amdgcn_cvt_pk_fp8_f32(hB,hB,0,false)&0xff);
    }
    // no barrier: wave-private h0 slot (same-wave LDS ordering)

    // ---- Phase C: u = wih1 @ h0own via MFMA ----
    f32x4 accu[4];
    #pragma unroll
    for(int c=0;c<4;c++) accu[c]=(f32x4){0.f,0.f,0.f,0.f};
    #pragma unroll
    for(int kt=0;kt<4;kt++){
      uint2 a0 = make_uint2(0,0);
      if(lm==0) a0 = *(const uint2*)((const char*)&h0own[w][0] + kt*32 + lg*8);
      i64 A0 = u2l(a0);
      #pragma unroll
      for(int c=0;c<4;c++){
        accu[c] = __builtin_amdgcn_mfma_f32_16x16x32_fp8_fp8(A0, u2l(W1f[kt][lg][colbase+c*16+lm]), accu[c], 0,0,0);
      }
    }
    {
      float su=0.f, squ=0.f;
      #pragma unroll
      for(int c=0;c<4;c++){ float x=accu[c][0]; su+=x; squ+=x*x; }
      float a  = wave_sum_partial(su);
      float bq = wave_sum_partial(squ);
      if(l==63){ red[p][32+w]=a; red[p][40+w]=bq; }
      if(l<16){
        #pragma unroll
        for(int c=0;c<4;c++) pu[p][colbase + c*16 + l] = accu[c][0];
      }
    }
    __syncthreads();                                      // bar2

    // ---- Phase D: layer-1 gates, REDUNDANT on all waves ----
    {
      float Su=0.f,Su2=0.f,Sv=0.f,Sv2=0.f;
      #pragma unroll
      for(int q=0;q<8;q++){ Su+=red[p][32+q]; Su2+=red[p][40+q]; Sv+=red[p][16+q]; Sv2+=red[p][24+q]; }
      float muu = Su*(1.f/512.f);
      float rsu = rsqrtf(Su2*(1.f/512.f) - muu*muu + 1e-5f);
      float muv = Sv*(1.f/512.f);
      float rsv = rsqrtf(Sv2*(1.f/512.f) - muv*muv + 1e-5f);
      float ashA[4], ashB[4];
      #pragma unroll
      for(int k=0;k<4;k++){
        int ia = l + 128*k, ib = l + 64 + 128*k;
        ashA[k] = (pu[p][ia]-muu)*rsu*lnC[ia] + lnD[ia]
                + (pv1[p][ia]-muv)*rsv*lnE[ia] + lnF[ia];
        ashB[k] = (pu[p][ib]-muu)*rsu*lnC[ib] + lnD[ib]
                + (pv1[p][ib]-muv)*rsv*lnE[ib] + lnF[ib];
      }
      float cpA = sigf(ashA[1])*c1rA + sigf(ashA[0])*tanh_fast(ashA[2]);
      float cpB = sigf(ashB[1])*c1rB + sigf(ashB[0])*tanh_fast(ashB[2]);
      float s  = wave_sum(cpA+cpB);
      float s2 = wave_sum(cpA*cpA+cpB*cpB);
      float muc = s*(1.f/128.f);
      float rsc = rsqrtf(s2*(1.f/128.f) - muc*muc + 1e-5f);
      c1rA = (cpA-muc)*rsc*cg1A + cb1A;
      c1rB = (cpB-muc)*rsc*cg1B + cb1B;
      float hA = sigf(ashA[3])*tanh_fast(c1rA);
      float hB = sigf(ashB[3])*tanh_fast(c1rB);
      ((unsigned char*)&h1own[w][0])[l]    = (unsigned char)(__builtin_amdgcn_cvt_pk_fp8_f32(hA,hA,0,false)&0xff);
      ((unsigned char*)&h1own[w][0])[l+64] = (unsigned char)(__builtin_amdgcn_cvt_pk_fp8_f32(hB,hB,0,false)&0xff);
      if(w==0){
        H1[((size_t)b*SSTEP+i)*HDIM + l]      = hA;
        H1[((size_t)b*SSTEP+i)*HDIM + l + 64] = hB;
      }
    }
    // no barrier: next phase A uses own h slots; red/pvv flip parity
    p ^= 1;
  }
}

// ---------------- logits: per-batch H1 @ key^T with mask ----------------
__global__ __launch_bounds__(512)
void logits_kernel(const float* __restrict__ key, const float* __restrict__ H1,
                   const int* __restrict__ en, const int* __restrict__ su,
                   float* __restrict__ out){
  const int b = blockIdx.x;
  const int ihalf = blockIdx.y;
  __shared__ float HsT[128][36];       // [k][i-local], padded
  __shared__ int firstsel[NP1];
  for(int t=threadIdx.x; t<32*HDIM; t+=512){
    int il = t>>7, k = t&127;
    HsT[k][il] = H1[(size_t)b*SSTEP*HDIM + (size_t)(ihalf*32+il)*HDIM + k];
  }
  for(int t=threadIdx.x; t<NP1; t+=512) firstsel[t] = 1<<30;
  __syncthreads();
  if(threadIdx.x < SSTEP) atomicMin(&firstsel[su[b*SSTEP+threadIdx.x]], (int)threadIdx.x);
  __syncthreads();
  const int enb = en[b];
  const int tn = threadIdx.x & 255;
  const int ig = threadIdx.x >> 8;          // 0,1
  const int i0l = ig*16;
  const int ig0 = ihalf*32 + i0l;           // global i base
  float acc0[16], acc1[16];
  #pragma unroll
  for(int q=0;q<16;q++){ acc0[q]=0.f; acc1[q]=0.f; }
  const float* kr0 = key + ((size_t)b*NP1 + tn)*KDIM;
  const float* kr1 = key + ((size_t)b*NP1 + tn + 256)*KDIM;
  for(int k=0;k<KDIM;k+=4){
    float4 kv0 = *(const float4*)&kr0[k];
    float4 kv1 = *(const float4*)&kr1[k];
    float k0a[4] = {kv0.x,kv0.y,kv0.z,kv0.w};
    float k1a[4] = {kv1.x,kv1.y,kv1.z,kv1.w};
    #pragma unroll
    for(int kk=0;kk<4;kk++){
      float4 h0 = *(const float4*)&HsT[k+kk][i0l+0];
      float4 h1 = *(const float4*)&HsT[k+kk][i0l+4];
      float4 h2 = *(const float4*)&HsT[k+kk][i0l+8];
      float4 h3 = *(const float4*)&HsT[k+kk][i0l+12];
      float ka = k0a[kk], kb = k1a[kk];
      acc0[ 0]=fmaf(ka,h0.x,acc0[ 0]); acc0[ 1]=fmaf(ka,h0.y,acc0[ 1]);
      acc0[ 2]=fmaf(ka,h0.z,acc0[ 2]); acc0[ 3]=fmaf(ka,h0.w,acc0[ 3]);
      acc0[ 4]=fmaf(ka,h1.x,acc0[ 4]); acc0[ 5]=fmaf(ka,h1.y,acc0[ 5]);
      acc0[ 6]=fmaf(ka,h1.z,acc0[ 6]); acc0[ 7]=fmaf(ka,h1.w,acc0[ 7]);
      acc0[ 8]=fmaf(ka,h2.x,acc0[ 8]); acc0[ 9]=fmaf(ka,h2.y,acc0[ 9]);
      acc0[10]=fmaf(ka,h2.z,acc0[10]); acc0[11]=fmaf(ka,h2.w,acc0[11]);
      acc0[12]=fmaf(ka,h3.x,acc0[12]); acc0[13]=fmaf(ka,h3.y,acc0[13]);
      acc0[14]=fmaf(ka,h3.z,acc0[14]); acc0[15]=fmaf(ka,h3.w,acc0[15]);
      acc1[ 0]=fmaf(kb,h0.x,acc1[ 0]); acc1[ 1]=fmaf(kb,h0.y,acc1[ 1]);
      acc1[ 2]=fmaf(kb,h0.z,acc1[ 2]); acc1[ 3]=fmaf(kb,h0.w,acc1[ 3]);
      acc1[ 4]=fmaf(kb,h1.x,acc1[ 4]); acc1[ 5]=fmaf(kb,h1.y,acc1[ 5]);
      acc1[ 6]=fmaf(kb,h1.z,acc1[ 6]); acc1[ 7]=fmaf(kb,h1.w,acc1[ 7]);
      acc1[ 8]=fmaf(kb,h2.x,acc1[ 8]); acc1[ 9]=fmaf(kb,h2.y,acc1[ 9]);
      acc1[10]=fmaf(kb,h2.z,acc1[10]); acc1[11]=fmaf(kb,h2.w,acc1[11]);
      acc1[12]=fmaf(kb,h3.x,acc1[12]); acc1[13]=fmaf(kb,h3.y,acc1[13]);
      acc1[14]=fmaf(kb,h3.z,acc1[14]); acc1[15]=fmaf(kb,h3.w,acc1[15]);
    }
  }
  const int n0 = tn, n1 = tn + 256;
  const int fs0 = firstsel[n0], fs1 = firstsel[n1];
  #pragma unroll
  for(int q=0;q<16;q++){
    int i = ig0 + q;
    bool m0 = (n0 <= enb) && (fs0 >= i) && !(i==0 && n0==enb);
    bool m1 = (n1 <= enb) && (fs1 >= i) && !(i==0 && n1==enb);
    out[((size_t)b*SSTEP + i)*NP1 + n0] = m0 ? acc0[q] : NEGV;
    out[((size_t)b*SSTEP + i)*NP1 + n1] = m1 ? acc1[q] : NEGV;
  }
  if(threadIdx.x < 32){
    int i = ihalf*32 + threadIdx.x;
    out[((size_t)b*SSTEP + i)*NP1 + 512] = NEGV;   // n=512 always masked (enb<512)
  }
}

// ---------------- P = s1 @ e2_w^T, fused ae epilogue + sun ----------------
__global__ __launch_bounds__(256)
void ae_gemm(const float* __restrict__ A, const float* __restrict__ B,
             const float* __restrict__ emb, const float* __restrict__ e2_b,
             const float* __restrict__ ng, const int* __restrict__ sun,
             float* __restrict__ out){
  const size_t AE_OFF = (size_t)BSZ*SSTEP*NP1;
  const size_t SUN_OFF = AE_OFF + (size_t)BSZ*DIN;
  __shared__ ushort Abf[64][72];
  __shared__ ushort Bbf[64][72];
  const int t = threadIdx.x;
  const int bm = blockIdx.x, bn = blockIdx.y;
  const int w = t>>6, l = t&63;
  const int lm = l&15, lg = l>>4;
  const int r0 = w*16;
  f32x4 acc[4];
  #pragma unroll
  for(int f=0;f<4;f++) acc[f] = (f32x4){0.f,0.f,0.f,0.f};
  for(int k0=0;k0<256;k0+=64){
    #pragma unroll
    for(int i=0;i<4;i++){
      int idx = t + i*256;
      int row = idx>>4, c4 = (idx&15)<<2;
      float4 v = *(const float4*)&A[((size_t)bm*64+row)*256 + k0 + c4];
      ushort4 u;
      u.x = __float_as_uint(v.x)>>16; u.y = __float_as_uint(v.y)>>16;
      u.z = __float_as_uint(v.z)>>16; u.w = __float_as_uint(v.w)>>16;
      *(ushort4*)&Abf[row][c4] = u;
    }
    #pragma unroll
    for(int i=0;i<4;i++){
      int idx = t + i*256;
      int row = idx>>4, c4 = (idx&15)<<2;
      float4 v = *(const float4*)&B[((size_t)bn*64+row)*256 + k0 + c4];
      ushort4 u;
      u.x = __float_as_uint(v.x)>>16; u.y = __float_as_uint(v.y)>>16;
      u.z = __float_as_uint(v.z)>>16; u.w = __float_as_uint(v.w)>>16;
      *(ushort4*)&Bbf[row][c4] = u;
    }
    __syncthreads();
    #pragma unroll
    for(int kk=0;kk<64;kk+=32){
      bf16x8 a = *(const bf16x8*)&Abf[r0+lm][kk + lg*8];
      #pragma unroll
      for(int f=0;f<4;f++){
        bf16x8 b = *(const bf16x8*)&Bbf[f*16+lm][kk + lg*8];
        acc[f] = __builtin_amdgcn_mfma_f32_16x16x32_bf16(a, b, acc[f], 0,0,0);
      }
    }
    __syncthreads();
  }
  #pragma unroll
  for(int f=0;f<4;f++){
    int gcol = bn*64 + f*16 + lm;
    float eb = e2_b[gcol];
    #pragma unroll
    for(int r=0;r<4;r++){
      int grow = bm*64 + r0 + lg*4 + r;
      size_t o = (size_t)grow*DIN + gcol;
      out[AE_OFF + o] = emb[o] + acc[f][r] + ng[grow]*eb;
    }
  }
  if(bm==0 && bn==0 && t<BSZ) out[SUN_OFF + t] = (float)sun[t];
}

// ---------------- launch ----------------
extern "C" void kernel_launch(void* const* d_in, const int* in_sizes, int n_in,
                              void* d_out, int out_size, void* d_ws, size_t ws_size,
                              hipStream_t stream){
  const float* emb     = (const float*)d_in[0];
  const float* ent     = (const float*)d_in[1];
  const float* key_w   = (const float*)d_in[2];
  const float* key_b   = (const float*)d_in[3];
  const float* q1_w    = (const float*)d_in[4];
  const float* q1_b    = (const float*)d_in[5];
  const float* q2_w    = (const float*)d_in[6];
  const float* q2_b    = (const float*)d_in[7];
  const float* e1_w    = (const float*)d_in[8];
  const float* e1_b    = (const float*)d_in[9];
  const float* e2_w    = (const float*)d_in[10];
  const float* e2_b    = (const float*)d_in[11];
  const float* end_emb = (const float*)d_in[12];
  const float* wih     = (const float*)d_in[13];
  const float* whh     = (const float*)d_in[14];
  const float* ln_ig   = (const float*)d_in[15];
  const float* ln_ib   = (const float*)d_in[16];
  const float* ln_hg   = (const float*)d_in[17];
  const float* ln_hb   = (const float*)d_in[18];
  const float* ln_cg   = (const float*)d_in[19];
  const float* ln_cb   = (const float*)d_in[20];
  const int* en  = (const int*)d_in[21];
  const int* su  = (const int*)d_in[22];
  const int* sun = (const int*)d_in[23];
  float* out = (float*)d_out;
  float* ws  = (float*)d_ws;

  // workspace layout (float units)
  const size_t o_key = 0;                       // 128*513*128 = 8,404,992
  const size_t o_T1  = o_key + 8404992;         // 2,097,152
  const size_t o_q1e = o_T1  + 2097152;         // 65,536
  const size_t o_c0  = o_q1e + 65536;           // 1,024 (256 used)
  const size_t o_U0  = o_c0  + 1024;            // 32,768
  const size_t o_Q1K = o_U0  + 32768;           // 2,097,152
  const size_t o_RU  = o_Q1K + 2097152;         // 2,097,152
  const size_t o_X   = o_RU  + 2097152;         // 1,048,576
  const size_t o_G0  = o_X   + 1048576;         // 4,194,304
  const size_t o_s1  = o_G0  + 4194304;         // 32,768
  const size_t o_ng  = o_s1  + 32768;           // 1,024 (128 used)
  const size_t o_H1  = o_ng  + 1024;            // 1,048,576

  // 1) key = ent @ key_w^T + key_b (MFMA, KEYMAP rows, end-row folded in)
  key_gemm_mfma<<<1024,256,0,stream>>>(ent, key_w, key_b, en, end_emb, ws+o_key);
  // 2) T1 = relu(gather(key,su)/512 @ e1_w^T + e1_b)
  mfma_gemm<false,true,true><<<dim3(128,4),256,0,stream>>>(ws+o_key, e1_w, e1_b, ws+o_T1,
                                                           8192,256,128, su, INV_MAX);
  // 3) q1e = q1_w @ e2_w  (BKMAJOR)
  mfma_gemm<true,false,false><<<dim3(4,4),256,0,stream>>>(q1_w, e2_w, nullptr, ws+o_q1e,
                                                          256,256,1024, nullptr, 1.f);
  // 4) c0 = q1_w @ e2_b
  c0_kernel<<<256,256,0,stream>>>(q1_w, e2_b, ws+o_c0);
  // 5) U0 = emb @ q1_w^T + q1_b
  mfma_gemm<false,false,false><<<dim3(2,4),256,0,stream>>>(emb, q1_w, q1_b, ws+o_U0,
                                                           128,256,1024, nullptr, 1.f);
  // 6) Q1K = T1 @ q1e^T
  mfma_gemm<false,false,false><<<dim3(128,4),256,0,stream>>>(ws+o_T1, ws+o_q1e, nullptr, ws+o_Q1K,
                                                             8192,256,256, nullptr, 1.f);
  // 7) gated exclusive prefix -> relu(U), s1, ng
  prefix_kernel<<<128,256,0,stream>>>(ws+o_U0, ws+o_Q1K, ws+o_c0, ws+o_T1, su, en, sun,
                                      ws+o_RU, ws+o_s1, ws+o_ng);
  // 8) X = RU @ q2_w^T + q2_b
  mfma_gemm<false,false,false><<<dim3(128,2),256,0,stream>>>(ws+o_RU, q2_w, q2_b, ws+o_X,
                                                             8192,128,256, nullptr, 1.f);
  // 9) G0 = LN(X @ wih0^T)  (fused GEMM+LN)
  g0_gemm_ln<<<512,256,0,stream>>>(ws+o_X, wih, ln_ig, ln_ib, ws+o_G0);
  // 10) serial LN-LSTM scan -> H1 (MFMA matvecs, 2 barriers/step)
  lstm_serial<<<128,512,0,stream>>>(wih, whh, ws+o_G0,
                                    ln_ig, ln_ib, ln_hg, ln_hb, ln_cg, ln_cb, ws+o_H1);
  // 11) logits (masked) directly into d_out
  logits_kernel<<<dim3(128,2),512,0,stream>>>(ws+o_key, ws+o_H1, en, su, out);
  // 12) ae = emb + s1 @ e2_w^T + ng*e2_b ; sun passthrough
  ae_gemm<<<dim3(2,16),256,0,stream>>>(ws+o_s1, e2_w, emb, e2_b, ws+o_ng, sun, out);
}

// Round 18
// 440.024 us; speedup vs baseline: 1.1395x; 1.1395x over previous
//
#include <hip/hip_runtime.h>
#include <hip/hip_bf16.h>
#include <math.h>

#define BSZ   128
#define NENT  512
#define NP1   513
#define DENT  256
#define KDIM  128
#define DIN   1024
#define DF    256
#define HDIM  128
#define SSTEP 64
#define G4    512
#define NEGV  (-1e9f)
#define INV_MAX (1.0f/512.0f)

typedef float v2f __attribute__((ext_vector_type(2)));
typedef __attribute__((ext_vector_type(8))) short bf16x8;
typedef __attribute__((ext_vector_type(4))) float f32x4;
typedef long i64;

// ---------------- helpers ----------------
__device__ inline float sigf(float x){ return 1.f/(1.f+__expf(-x)); }
__device__ inline float tanh_fast(float x){ float e=__expf(2.f*x); return 1.f - 2.f/(e+1.f); }

__device__ inline float sum16_partial(float x){
  x += __int_as_float(__builtin_amdgcn_update_dpp(0, __float_as_int(x), 0x111, 0xf, 0xf, true));
  x += __int_as_float(__builtin_amdgcn_update_dpp(0, __float_as_int(x), 0x112, 0xf, 0xf, true));
  x += __int_as_float(__builtin_amdgcn_update_dpp(0, __float_as_int(x), 0x114, 0xf, 0xf, true));
  x += __int_as_float(__builtin_amdgcn_update_dpp(0, __float_as_int(x), 0x118, 0xf, 0xf, true));
  return x;
}
__device__ inline float wave_sum_partial(float x){
  x = sum16_partial(x);
  x += __int_as_float(__builtin_amdgcn_update_dpp(0, __float_as_int(x), 0x142, 0xa, 0xf, true));
  x += __int_as_float(__builtin_amdgcn_update_dpp(0, __float_as_int(x), 0x143, 0xc, 0xf, true));
  return x;
}
__device__ inline float wave_sum(float x){
  return __int_as_float(__builtin_amdgcn_readlane(__float_as_int(wave_sum_partial(x)), 63));
}

__device__ inline unsigned pk8(float4 f){
  int r = 0;
  r = __builtin_amdgcn_cvt_pk_fp8_f32(f.x, f.y, r, false);
  r = __builtin_amdgcn_cvt_pk_fp8_f32(f.z, f.w, r, true);
  return (unsigned)r;
}
__device__ inline i64 u2l(uint2 v){ union{uint2 u; i64 l;} x; x.u=v; return x.l; }

// block = 512 threads (8 waves).
__device__ inline float2 block_reduce2(float x, float y, float* red){
  float sx0 = wave_sum_partial(x), sy0 = wave_sum_partial(y);
  int w = threadIdx.x>>6;
  __syncthreads();
  if((threadIdx.x&63)==63){ red[w]=sx0; red[8+w]=sy0; }
  __syncthreads();
  float sx=0.f, sy=0.f;
  #pragma unroll
  for(int q=0;q<8;q++){ sx+=red[q]; sy+=red[8+q]; }
  return make_float2(sx,sy);
}

// ---------------- generic MFMA GEMM: C[M,N] = act(A[M,K] @ B^T + bias) ----------------
template<bool BKMAJOR, bool RELU, bool GATHER>
__global__ __launch_bounds__(256)
void mfma_gemm(const float* __restrict__ A, const float* __restrict__ B,
               const float* __restrict__ bias, float* __restrict__ C,
               int M, int N, int K,
               const int* __restrict__ gidx, float scale){
  __shared__ ushort Abf[64][72];
  __shared__ ushort Bbf[64][72];
  const int t = threadIdx.x;
  const int bm = blockIdx.x, bn = blockIdx.y;
  const int w = t>>6, l = t&63;
  const int lm = l&15, lg = l>>4;
  const int r0 = w*16;
  f32x4 acc[4];
  #pragma unroll
  for(int f=0;f<4;f++) acc[f] = (f32x4){0.f,0.f,0.f,0.f};

  for(int k0=0;k0<K;k0+=64){
    #pragma unroll
    for(int i=0;i<4;i++){
      int idx = t + i*256;
      int row = idx>>4, c4 = (idx&15)<<2;
      const float* src;
      if(GATHER){
        int gr = bm*64+row;
        src = &A[((size_t)(gr>>6)*NP1 + gidx[gr])*(size_t)K + k0 + c4];
      } else {
        src = &A[((size_t)bm*64+row)*K + k0 + c4];
      }
      float4 v = *(const float4*)src;
      if(GATHER){ v.x*=scale; v.y*=scale; v.z*=scale; v.w*=scale; }
      ushort4 u;
      u.x = __float_as_uint(v.x)>>16; u.y = __float_as_uint(v.y)>>16;
      u.z = __float_as_uint(v.z)>>16; u.w = __float_as_uint(v.w)>>16;
      *(ushort4*)&Abf[row][c4] = u;
    }
    if(!BKMAJOR){
      #pragma unroll
      for(int i=0;i<4;i++){
        int idx = t + i*256;
        int row = idx>>4, c4 = (idx&15)<<2;
        float4 v = *(const float4*)&B[((size_t)bn*64+row)*K + k0 + c4];
        ushort4 u;
        u.x = __float_as_uint(v.x)>>16; u.y = __float_as_uint(v.y)>>16;
        u.z = __float_as_uint(v.z)>>16; u.w = __float_as_uint(v.w)>>16;
        *(ushort4*)&Bbf[row][c4] = u;
      }
    } else {
      #pragma unroll
      for(int i=0;i<4;i++){
        int idx = t + i*256;
        int kr = idx>>4, n4 = (idx&15)<<2;
        float4 v = *(const float4*)&B[(size_t)(k0+kr)*N + bn*64 + n4];
        Bbf[n4+0][kr] = __float_as_uint(v.x)>>16;
        Bbf[n4+1][kr] = __float_as_uint(v.y)>>16;
        Bbf[n4+2][kr] = __float_as_uint(v.z)>>16;
        Bbf[n4+3][kr] = __float_as_uint(v.w)>>16;
      }
    }
    __syncthreads();
    #pragma unroll
    for(int kk=0;kk<64;kk+=32){
      bf16x8 a = *(const bf16x8*)&Abf[r0+lm][kk + lg*8];
      #pragma unroll
      for(int f=0;f<4;f++){
        bf16x8 b = *(const bf16x8*)&Bbf[f*16+lm][kk + lg*8];
        acc[f] = __builtin_amdgcn_mfma_f32_16x16x32_bf16(a, b, acc[f], 0,0,0);
      }
    }
    __syncthreads();
  }
  #pragma unroll
  for(int f=0;f<4;f++){
    int gcol = bn*64 + f*16 + lm;
    float bb = bias ? bias[gcol] : 0.f;
    #pragma unroll
    for(int r=0;r<4;r++){
      int grow = bm*64 + r0 + lg*4 + r;
      float v = acc[f][r] + bb;
      if(RELU) v = fmaxf(v, 0.f);
      C[(size_t)grow*N + gcol] = v;
    }
  }
}

// ---------------- MFMA key GEMM: key = ent @ key_w^T + key_b, end-row folded in -------
__global__ __launch_bounds__(256)
void key_gemm_mfma(const float* __restrict__ A, const float* __restrict__ W,
                   const float* __restrict__ bias, const int* __restrict__ en,
                   const float* __restrict__ end_emb, float* __restrict__ C){
  __shared__ ushort Abf[64][264];
  __shared__ ushort Bbf[128][264];
  __shared__ float bs[128];
  const int t = threadIdx.x;
  const int bm = blockIdx.x;
  #pragma unroll
  for(int i=0;i<16;i++){
    int idx = t + i*256;
    int row = idx>>6, c4 = (idx&63)<<2;
    float4 v = *(const float4*)&A[((size_t)bm*64+row)*256 + c4];
    ushort4 u;
    u.x = __float_as_uint(v.x)>>16; u.y = __float_as_uint(v.y)>>16;
    u.z = __float_as_uint(v.z)>>16; u.w = __float_as_uint(v.w)>>16;
    *(ushort4*)&Abf[row][c4] = u;
  }
  #pragma unroll
  for(int i=0;i<32;i++){
    int idx = t + i*256;
    int row = idx>>6, c4 = (idx&63)<<2;
    float4 v = *(const float4*)&W[(size_t)row*256 + c4];
    ushort4 u;
    u.x = __float_as_uint(v.x)>>16; u.y = __float_as_uint(v.y)>>16;
    u.z = __float_as_uint(v.z)>>16; u.w = __float_as_uint(v.w)>>16;
    *(ushort4*)&Bbf[row][c4] = u;
  }
  if(t<128) bs[t] = bias[t];
  __syncthreads();
  const int w = t>>6, l = t&63;
  const int lm = l&15, lg = l>>4;
  const int r0 = w*16;
  f32x4 acc[8];
  #pragma unroll
  for(int f=0;f<8;f++) acc[f] = (f32x4){0.f,0.f,0.f,0.f};
  #pragma unroll
  for(int k0=0;k0<256;k0+=32){
    bf16x8 a = *(const bf16x8*)&Abf[r0+lm][k0 + lg*8];
    #pragma unroll
    for(int f=0;f<8;f++){
      bf16x8 b = *(const bf16x8*)&Bbf[f*16+lm][k0 + lg*8];
      acc[f] = __builtin_amdgcn_mfma_f32_16x16x32_bf16(a, b, acc[f], 0,0,0);
    }
  }
  #pragma unroll
  for(int f=0;f<8;f++){
    int gcol = f*16 + lm;
    float bb = bs[gcol];
    float ev = end_emb[gcol];
    #pragma unroll
    for(int r=0;r<4;r++){
      int grow = bm*64 + r0 + lg*4 + r;
      int bq = grow>>9, n = grow&511;
      size_t orow = (size_t)bq*NP1 + n;
      float v = acc[f][r] + bb;
      if(n == en[bq]) v = ev;       // end-embedding row (reference .set)
      C[orow*KDIM + gcol] = v;
    }
  }
}

// ---------------- G0 = LN(X @ wih0^T) : 512 blocks x 16 rows, N=512, K=128 ----------------
__global__ __launch_bounds__(256)
void g0_gemm_ln(const float* __restrict__ X, const float* __restrict__ W,
                const float* __restrict__ gam, const float* __restrict__ bet,
                float* __restrict__ G0){
  __shared__ ushort Abf[16][136];
  __shared__ float redS[16][4], redQ[16][4];
  const int t = threadIdx.x, bm = blockIdx.x;
  const int w = t>>6, l = t&63, lm = l&15, lg = l>>4;
  {
    int idx = t*8;
    int row = idx>>7, c = idx&127;
    const float* src = &X[((size_t)bm*16+row)*128 + c];
    float4 a = *(const float4*)src;
    float4 d = *(const float4*)(src+4);
    ushort4 u0, u1;
    u0.x=__float_as_uint(a.x)>>16; u0.y=__float_as_uint(a.y)>>16;
    u0.z=__float_as_uint(a.z)>>16; u0.w=__float_as_uint(a.w)>>16;
    u1.x=__float_as_uint(d.x)>>16; u1.y=__float_as_uint(d.y)>>16;
    u1.z=__float_as_uint(d.z)>>16; u1.w=__float_as_uint(d.w)>>16;
    *(ushort4*)&Abf[row][c] = u0;
    *(ushort4*)&Abf[row][c+4] = u1;
  }
  __syncthreads();
  f32x4 acc[8];
  #pragma unroll
  for(int f=0;f<8;f++) acc[f] = (f32x4){0.f,0.f,0.f,0.f};
  #pragma unroll
  for(int kt=0;kt<4;kt++){
    int k0 = kt*32;
    bf16x8 a = *(const bf16x8*)&Abf[lm][k0 + lg*8];
    #pragma unroll
    for(int f=0;f<8;f++){
      int brow = w*128 + f*16 + lm;
      const float* bp = &W[(size_t)brow*128 + k0 + lg*8];
      float4 b0 = *(const float4*)bp;
      float4 b1 = *(const float4*)(bp+4);
      bf16x8 bfr;
      bfr[0]=(short)(__float_as_uint(b0.x)>>16); bfr[1]=(short)(__float_as_uint(b0.y)>>16);
      bfr[2]=(short)(__float_as_uint(b0.z)>>16); bfr[3]=(short)(__float_as_uint(b0.w)>>16);
      bfr[4]=(short)(__float_as_uint(b1.x)>>16); bfr[5]=(short)(__float_as_uint(b1.y)>>16);
      bfr[6]=(short)(__float_as_uint(b1.z)>>16); bfr[7]=(short)(__float_as_uint(b1.w)>>16);
      acc[f] = __builtin_amdgcn_mfma_f32_16x16x32_bf16(a, bfr, acc[f], 0,0,0);
    }
  }
  float mu[4], rs[4];
  #pragma unroll
  for(int r=0;r<4;r++){
    float s=0.f, q=0.f;
    #pragma unroll
    for(int f=0;f<8;f++){ float x=acc[f][r]; s+=x; q+=x*x; }
    s = sum16_partial(s);
    q = sum16_partial(q);
    if(lm==15){ redS[lg*4+r][w]=s; redQ[lg*4+r][w]=q; }
  }
  __syncthreads();
  #pragma unroll
  for(int r=0;r<4;r++){
    int row = lg*4+r;
    float S = redS[row][0]+redS[row][1]+redS[row][2]+redS[row][3];
    float Q = redQ[row][0]+redQ[row][1]+redQ[row][2]+redQ[row][3];
    mu[r] = S*(1.f/512.f);
    rs[r] = rsqrtf(Q*(1.f/512.f) - mu[r]*mu[r] + 1e-5f);
  }
  #pragma unroll
  for(int f=0;f<8;f++){
    int col = w*128 + f*16 + lm;
    float g = gam[col], bt = bet[col];
    #pragma unroll
    for(int r=0;r<4;r++){
      int grow = bm*16 + lg*4 + r;
      G0[(size_t)grow*G4 + col] = (acc[f][r]-mu[r])*rs[r]*g + bt;
    }
  }
}

// ---------------- c0v[f] = q1_w[f,:] . e2_b ----------------
__global__ __launch_bounds__(256)
void c0_kernel(const float* __restrict__ q1_w, const float* __restrict__ e2_b,
               float* __restrict__ c0v){
  __shared__ float red[4];
  int f = blockIdx.x, t = threadIdx.x;
  float4 a = *(const float4*)&q1_w[(size_t)f*DIN + t*4];
  float4 e = *(const float4*)&e2_b[t*4];
  float p = a.x*e.x + a.y*e.y + a.z*e.z + a.w*e.w;
  float s = wave_sum_partial(p);
  if((t&63)==63) red[t>>6] = s;
  __syncthreads();
  if(t==0) c0v[f] = red[0]+red[1]+red[2]+red[3];
}

// ---------------- gated exclusive prefix over steps; emits relu(U), s1, ng ----------------
__global__ void prefix_kernel(const float* __restrict__ U0, const float* __restrict__ Q1K,
                              const float* __restrict__ c0v, const float* __restrict__ T1,
                              const int* __restrict__ su, const int* __restrict__ en,
                              const int* __restrict__ sun,
                              float* __restrict__ RU, float* __restrict__ s1,
                              float* __restrict__ ngout){
  int b = blockIdx.x, f = threadIdx.x;    // 128 x 256
  float acc = U0[b*DF+f];
  float c0f = c0v[f];
  float s1a = 0.f, ng = 0.f;
  int enb = en[b], sunb = sun[b];
  for(int j=0;j<SSTEP;j++){
    int r = b*SSTEP+j;
    float q = Q1K[(size_t)r*DF+f];
    float tt = T1[(size_t)r*DF+f];
    RU[(size_t)r*DF+f] = fmaxf(acc,0.f);
    int sj = su[r];
    float g = ((j+1)<=sunb && sj!=enb) ? 1.f : 0.f;
    acc = fmaf(g, q + c0f, acc);
    s1a = fmaf(g, tt, s1a);
    ng += g;
  }
  s1[b*DF+f]=s1a;
  if(f==0) ngout[b]=ng;
}

// ---------------- serial 2-layer LN-LSTM scan (R16 structure, best measured 213us) ----
// MFMA fp8 matvecs (h as 1-valid-row A operand), fp8 weights in LDS frags / regs,
// 1-wave gate phases, 4 barriers/step, DPP reductions.
__global__ __launch_bounds__(512)
__attribute__((amdgpu_waves_per_eu(2,2)))
void lstm_serial(const float* __restrict__ wih, const float* __restrict__ whh,
                 const float* __restrict__ G0,
                 const float* __restrict__ ln_ig, const float* __restrict__ ln_ib,
                 const float* __restrict__ ln_hg, const float* __restrict__ ln_hb,
                 const float* __restrict__ ln_cg, const float* __restrict__ ln_cb,
                 float* __restrict__ H1){
  const int b = blockIdx.x;
  const int j = threadIdx.x;
  const int w = j>>6, l = j&63;
  const int lm = l&15, lg = l>>4;
  __shared__ uint2 W0f[4][4][512];     // whh0 fp8 frags [kt][lg][col]  (64 KB)
  __shared__ uint2 W1f[4][4][512];     // wih1 fp8 frags                (64 KB)
  __shared__ uint4 h0q8[8], h1q8[8];   // h as fp8 (128 B each)
  __shared__ float pvv[512], pv1[512];
  __shared__ float lnA[512], lnB[512], lnC[512], lnD[512], lnE[512], lnF[512];
  __shared__ float red[32];

  // one-time staging: pack row j of whh0 / wih1 into fragment-major LDS
  {
    unsigned dw[32];
    #pragma unroll
    for(int q=0;q<32;q++) dw[q] = pk8(*(const float4*)&whh[(size_t)j*KDIM + q*4]);
    #pragma unroll
    for(int kt=0;kt<4;kt++)
      #pragma unroll
      for(int g=0;g<4;g++)
        W0f[kt][g][j] = make_uint2(dw[kt*8+g*2], dw[kt*8+g*2+1]);
    #pragma unroll
    for(int q=0;q<32;q++) dw[q] = pk8(*(const float4*)&wih[65536 + (size_t)j*KDIM + q*4]);
    #pragma unroll
    for(int kt=0;kt<4;kt++)
      #pragma unroll
      for(int g=0;g<4;g++)
        W1f[kt][g][j] = make_uint2(dw[kt*8+g*2], dw[kt*8+g*2+1]);
  }
  // whh1 fragments in registers: w2f[c][kt] = W2[w*64+c*16+lm][kt*32+lg*8 ..+8]
  uint2 w2f[4][4];
  #pragma unroll
  for(int c=0;c<4;c++){
    int row = w*64 + c*16 + lm;
    #pragma unroll
    for(int kt=0;kt<4;kt++){
      int k0 = kt*32 + lg*8;
      float4 x0 = *(const float4*)&whh[65536 + (size_t)row*KDIM + k0];
      float4 x1 = *(const float4*)&whh[65536 + (size_t)row*KDIM + k0 + 4];
      w2f[c][kt] = make_uint2(pk8(x0), pk8(x1));
    }
  }
  lnA[j] = ln_hg[j];     lnB[j] = ln_hb[j];
  lnC[j] = ln_ig[512+j]; lnD[j] = ln_ib[512+j];
  lnE[j] = ln_hg[512+j]; lnF[j] = ln_hb[512+j];

  float cg0A=0.f,cb0A=0.f,cg0B=0.f,cb0B=0.f;
  float cg1A=0.f,cb1A=0.f,cg1B=0.f,cb1B=0.f;
  float c0rA=0.f,c0rB=0.f,c1rA=0.f,c1rB=0.f;
  if(j<64){
    cg0A=ln_cg[j];      cb0A=ln_cb[j];
    cg0B=ln_cg[j+64];   cb0B=ln_cb[j+64];
    cg1A=ln_cg[128+j];    cb1A=ln_cb[128+j];
    cg1B=ln_cg[128+j+64]; cb1B=ln_cb[128+j+64];
  }
  if(j<8){ h0q8[j]=(uint4){0,0,0,0}; h1q8[j]=(uint4){0,0,0,0}; }
  __syncthreads();

  const int colbase = w*64;

  for(int i=0;i<SSTEP;i++){
    float g0a[4], g0b[4];
    if(j<64){
      const float* gp = &G0[((size_t)b*SSTEP+i)*G4];
      #pragma unroll
      for(int k=0;k<4;k++){ g0a[k]=gp[j+128*k]; g0b[k]=gp[j+64+128*k]; }
    }

    // ---- Phase A: v = whh0@h0 (LDS frags) ; v1 = whh1@h1 (reg frags) via MFMA ----
    f32x4 accv[4], acc1[4];
    #pragma unroll
    for(int c=0;c<4;c++){ accv[c]=(f32x4){0.f,0.f,0.f,0.f}; acc1[c]=(f32x4){0.f,0.f,0.f,0.f}; }
    #pragma unroll
    for(int kt=0;kt<4;kt++){
      uint2 a0 = make_uint2(0,0), a1 = make_uint2(0,0);
      if(lm==0){
        a0 = *(const uint2*)((const char*)h0q8 + kt*32 + lg*8);
        a1 = *(const uint2*)((const char*)h1q8 + kt*32 + lg*8);
      }
      i64 A0 = u2l(a0), A1 = u2l(a1);
      #pragma unroll
      for(int c=0;c<4;c++){
        accv[c] = __builtin_amdgcn_mfma_f32_16x16x32_fp8_fp8(A0, u2l(W0f[kt][lg][colbase+c*16+lm]), accv[c], 0,0,0);
        acc1[c] = __builtin_amdgcn_mfma_f32_16x16x32_fp8_fp8(A1, u2l(w2f[c][kt]), acc1[c], 0,0,0);
      }
    }
    {
      float sv=0.f, sq=0.f, s1v=0.f, s1q=0.f;
      #pragma unroll
      for(int c=0;c<4;c++){
        float x = accv[c][0]; sv += x; sq += x*x;
        float y = acc1[c][0]; s1v += y; s1q += y*y;
      }
      float a  = wave_sum_partial(sv);
      float bq = wave_sum_partial(sq);
      float c2 = wave_sum_partial(s1v);
      float d  = wave_sum_partial(s1q);
      if(l==63){ red[w]=a; red[8+w]=bq; red[16+w]=c2; red[24+w]=d; }
      if(l<16){
        #pragma unroll
        for(int c=0;c<4;c++){
          pvv[colbase + c*16 + l] = accv[c][0];
          pv1[colbase + c*16 + l] = acc1[c][0];
        }
      }
    }
    __syncthreads();                                      // bar1

    // ---- Phase B: layer-0 gates on ONE wave (cells j, j+64) ----
    if(j<64){
      float S=0.f,S2=0.f;
      #pragma unroll
      for(int q=0;q<8;q++){ S+=red[q]; S2+=red[8+q]; }
      float mu = S*(1.f/512.f);
      float rs = rsqrtf(S2*(1.f/512.f) - mu*mu + 1e-5f);
      float ashA[4], ashB[4];
      #pragma unroll
      for(int k=0;k<4;k++){
        int ia = j + 128*k, ib = j + 64 + 128*k;
        ashA[k] = g0a[k] + (pvv[ia]-mu)*rs*lnA[ia] + lnB[ia];
        ashB[k] = g0b[k] + (pvv[ib]-mu)*rs*lnA[ib] + lnB[ib];
      }
      float cpA = sigf(ashA[1])*c0rA + sigf(ashA[0])*tanh_fast(ashA[2]);
      float cpB = sigf(ashB[1])*c0rB + sigf(ashB[0])*tanh_fast(ashB[2]);
      float s  = wave_sum(cpA+cpB);
      float s2 = wave_sum(cpA*cpA+cpB*cpB);
      float muc = s*(1.f/128.f);
      float rsc = rsqrtf(s2*(1.f/128.f) - muc*muc + 1e-5f);
      c0rA = (cpA-muc)*rsc*cg0A + cb0A;
      c0rB = (cpB-muc)*rsc*cg0B + cb0B;
      float hA = sigf(ashA[3])*tanh_fast(c0rA);
      float hB = sigf(ashB[3])*tanh_fast(c0rB);
      ((unsigned char*)h0q8)[j]    = (unsigned char)(__builtin_amdgcn_cvt_pk_fp8_f32(hA,hA,0,false)&0xff);
      ((unsigned char*)h0q8)[j+64] = (unsigned char)(__builtin_amdgcn_cvt_pk_fp8_f32(hB,hB,0,false)&0xff);
    }
    __syncthreads();                                      // bar2

    // ---- Phase C: u = wih1 @ h0_new (LDS frags) via MFMA ----
    f32x4 accu[4];
    #pragma unroll
    for(int c=0;c<4;c++) accu[c]=(f32x4){0.f,0.f,0.f,0.f};
    #pragma unroll
    for(int kt=0;kt<4;kt++){
      uint2 a0 = make_uint2(0,0);
      if(lm==0) a0 = *(const uint2*)((const char*)h0q8 + kt*32 + lg*8);
      i64 A0 = u2l(a0);
      #pragma unroll
      for(int c=0;c<4;c++){
        accu[c] = __builtin_amdgcn_mfma_f32_16x16x32_fp8_fp8(A0, u2l(W1f[kt][lg][colbase+c*16+lm]), accu[c], 0,0,0);
      }
    }
    {
      float su=0.f, squ=0.f;
      #pragma unroll
      for(int c=0;c<4;c++){ float x=accu[c][0]; su+=x; squ+=x*x; }
      float a  = wave_sum_partial(su);
      float bq = wave_sum_partial(squ);
      if(l==63){ red[w]=a; red[8+w]=bq; }
      if(l<16){
        #pragma unroll
        for(int c=0;c<4;c++) pvv[colbase + c*16 + l] = accu[c][0];
      }
    }
    __syncthreads();                                      // bar3

    // ---- Phase D: layer-1 gates on ONE wave ----
    if(j<64){
      float Su=0.f,Su2=0.f,Sv=0.f,Sv2=0.f;
      #pragma unroll
      for(int q=0;q<8;q++){ Su+=red[q]; Su2+=red[8+q]; Sv+=red[16+q]; Sv2+=red[24+q]; }
      float muu = Su*(1.f/512.f);
      float rsu = rsqrtf(Su2*(1.f/512.f) - muu*muu + 1e-5f);
      float muv = Sv*(1.f/512.f);
      float rsv = rsqrtf(Sv2*(1.f/512.f) - muv*muv + 1e-5f);
      float ashA[4], ashB[4];
      #pragma unroll
      for(int k=0;k<4;k++){
        int ia = j + 128*k, ib = j + 64 + 128*k;
        ashA[k] = (pvv[ia]-muu)*rsu*lnC[ia] + lnD[ia]
                + (pv1[ia]-muv)*rsv*lnE[ia] + lnF[ia];
        ashB[k] = (pvv[ib]-muu)*rsu*lnC[ib] + lnD[ib]
                + (pv1[ib]-muv)*rsv*lnE[ib] + lnF[ib];
      }
      float cpA = sigf(ashA[1])*c1rA + sigf(ashA[0])*tanh_fast(ashA[2]);
      float cpB = sigf(ashB[1])*c1rB + sigf(ashB[0])*tanh_fast(ashB[2]);
      float s  = wave_sum(cpA+cpB);
      float s2 = wave_sum(cpA*cpA+cpB*cpB);
      float muc = s*(1.f/128.f);
      float rsc = rsqrtf(s2*(1.f/128.f) - muc*muc + 1e-5f);
      c1rA = (cpA-muc)*rsc*cg1A + cb1A;
      c1rB = (cpB-muc)*rsc*cg1B + cb1B;
      float hA = sigf(ashA[3])*tanh_fast(c1rA);
      float hB = sigf(ashB[3])*tanh_fast(c1rB);
      ((unsigned char*)h1q8)[j]    = (unsigned char)(__builtin_amdgcn_cvt_pk_fp8_f32(hA,hA,0,false)&0xff);
      ((unsigned char*)h1q8)[j+64] = (unsigned char)(__builtin_amdgcn_cvt_pk_fp8_f32(hB,hB,0,false)&0xff);
      H1[((size_t)b*SSTEP+i)*HDIM + j]      = hA;
      H1[((size_t)b*SSTEP+i)*HDIM + j + 64] = hB;
    }
    __syncthreads();                                      // bar4
  }
}

// ---------------- logits: per-batch H1 @ key^T with mask ----------------
__global__ __launch_bounds__(512)
void logits_kernel(const float* __restrict__ key, const float* __restrict__ H1,
                   const int* __restrict__ en, const int* __restrict__ su,
                   float* __restrict__ out){
  const int b = blockIdx.x;
  const int ihalf = blockIdx.y;
  __shared__ float HsT[128][36];       // [k][i-local], padded
  __shared__ int firstsel[NP1];
  for(int t=threadIdx.x; t<32*HDIM; t+=512){
    int il = t>>7, k = t&127;
    HsT[k][il] = H1[(size_t)b*SSTEP*HDIM + (size_t)(ihalf*32+il)*HDIM + k];
  }
  for(int t=threadIdx.x; t<NP1; t+=512) firstsel[t] = 1<<30;
  __syncthreads();
  if(threadIdx.x < SSTEP) atomicMin(&firstsel[su[b*SSTEP+threadIdx.x]], (int)threadIdx.x);
  __syncthreads();
  const int enb = en[b];
  const int tn = threadIdx.x & 255;
  const int ig = threadIdx.x >> 8;          // 0,1
  const int i0l = ig*16;
  const int ig0 = ihalf*32 + i0l;           // global i base
  float acc0[16], acc1[16];
  #pragma unroll
  for(int q=0;q<16;q++){ acc0[q]=0.f; acc1[q]=0.f; }
  const float* kr0 = key + ((size_t)b*NP1 + tn)*KDIM;
  const float* kr1 = key + ((size_t)b*NP1 + tn + 256)*KDIM;
  for(int k=0;k<KDIM;k+=4){
    float4 kv0 = *(const float4*)&kr0[k];
    float4 kv1 = *(const float4*)&kr1[k];
    float k0a[4] = {kv0.x,kv0.y,kv0.z,kv0.w};
    float k1a[4] = {kv1.x,kv1.y,kv1.z,kv1.w};
    #pragma unroll
    for(int kk=0;kk<4;kk++){
      float4 h0 = *(const float4*)&HsT[k+kk][i0l+0];
      float4 h1 = *(const float4*)&HsT[k+kk][i0l+4];
      float4 h2 = *(const float4*)&HsT[k+kk][i0l+8];
      float4 h3 = *(const float4*)&HsT[k+kk][i0l+12];
      float ka = k0a[kk], kb = k1a[kk];
      acc0[ 0]=fmaf(ka,h0.x,acc0[ 0]); acc0[ 1]=fmaf(ka,h0.y,acc0[ 1]);
      acc0[ 2]=fmaf(ka,h0.z,acc0[ 2]); acc0[ 3]=fmaf(ka,h0.w,acc0[ 3]);
      acc0[ 4]=fmaf(ka,h1.x,acc0[ 4]); acc0[ 5]=fmaf(ka,h1.y,acc0[ 5]);
      acc0[ 6]=fmaf(ka,h1.z,acc0[ 6]); acc0[ 7]=fmaf(ka,h1.w,acc0[ 7]);
      acc0[ 8]=fmaf(ka,h2.x,acc0[ 8]); acc0[ 9]=fmaf(ka,h2.y,acc0[ 9]);
      acc0[10]=fmaf(ka,h2.z,acc0[10]); acc0[11]=fmaf(ka,h2.w,acc0[11]);
      acc0[12]=fmaf(ka,h3.x,acc0[12]); acc0[13]=fmaf(ka,h3.y,acc0[13]);
      acc0[14]=fmaf(ka,h3.z,acc0[14]); acc0[15]=fmaf(ka,h3.w,acc0[15]);
      acc1[ 0]=fmaf(kb,h0.x,acc1[ 0]); acc1[ 1]=fmaf(kb,h0.y,acc1[ 1]);
      acc1[ 2]=fmaf(kb,h0.z,acc1[ 2]); acc1[ 3]=fmaf(kb,h0.w,acc1[ 3]);
      acc1[ 4]=fmaf(kb,h1.x,acc1[ 4]); acc1[ 5]=fmaf(kb,h1.y,acc1[ 5]);
      acc1[ 6]=fmaf(kb,h1.z,acc1[ 6]); acc1[ 7]=fmaf(kb,h1.w,acc1[ 7]);
      acc1[ 8]=fmaf(kb,h2.x,acc1[ 8]); acc1[ 9]=fmaf(kb,h2.y,acc1[ 9]);
      acc1[10]=fmaf(kb,h2.z,acc1[10]); acc1[11]=fmaf(kb,h2.w,acc1[11]);
      acc1[12]=fmaf(kb,h3.x,acc1[12]); acc1[13]=fmaf(kb,h3.y,acc1[13]);
      acc1[14]=fmaf(kb,h3.z,acc1[14]); acc1[15]=fmaf(kb,h3.w,acc1[15]);
    }
  }
  const int n0 = tn, n1 = tn + 256;
  const int fs0 = firstsel[n0], fs1 = firstsel[n1];
  #pragma unroll
  for(int q=0;q<16;q++){
    int i = ig0 + q;
    bool m0 = (n0 <= enb) && (fs0 >= i) && !(i==0 && n0==enb);
    bool m1 = (n1 <= enb) && (fs1 >= i) && !(i==0 && n1==enb);
    out[((size_t)b*SSTEP + i)*NP1 + n0] = m0 ? acc0[q] : NEGV;
    out[((size_t)b*SSTEP + i)*NP1 + n1] = m1 ? acc1[q] : NEGV;
  }
  if(threadIdx.x < 32){
    int i = ihalf*32 + threadIdx.x;
    out[((size_t)b*SSTEP + i)*NP1 + 512] = NEGV;   // n=512 always masked (enb<512)
  }
}

// ---------------- P = s1 @ e2_w^T, fused ae epilogue + sun ----------------
__global__ __launch_bounds__(256)
void ae_gemm(const float* __restrict__ A, const float* __restrict__ B,
             const float* __restrict__ emb, const float* __restrict__ e2_b,
             const float* __restrict__ ng, const int* __restrict__ sun,
             float* __restrict__ out){
  const size_t AE_OFF = (size_t)BSZ*SSTEP*NP1;
  const size_t SUN_OFF = AE_OFF + (size_t)BSZ*DIN;
  __shared__ ushort Abf[64][72];
  __shared__ ushort Bbf[64][72];
  const int t = threadIdx.x;
  const int bm = blockIdx.x, bn = blockIdx.y;
  const int w = t>>6, l = t&63;
  const int lm = l&15, lg = l>>4;
  const int r0 = w*16;
  f32x4 acc[4];
  #pragma unroll
  for(int f=0;f<4;f++) acc[f] = (f32x4){0.f,0.f,0.f,0.f};
  for(int k0=0;k0<256;k0+=64){
    #pragma unroll
    for(int i=0;i<4;i++){
      int idx = t + i*256;
      int row = idx>>4, c4 = (idx&15)<<2;
      float4 v = *(const float4*)&A[((size_t)bm*64+row)*256 + k0 + c4];
      ushort4 u;
      u.x = __float_as_uint(v.x)>>16; u.y = __float_as_uint(v.y)>>16;
      u.z = __float_as_uint(v.z)>>16; u.w = __float_as_uint(v.w)>>16;
      *(ushort4*)&Abf[row][c4] = u;
    }
    #pragma unroll
    for(int i=0;i<4;i++){
      int idx = t + i*256;
      int row = idx>>4, c4 = (idx&15)<<2;
      float4 v = *(const float4*)&B[((size_t)bn*64+row)*256 + k0 + c4];
      ushort4 u;
      u.x = __float_as_uint(v.x)>>16; u.y = __float_as_uint(v.y)>>16;
      u.z = __float_as_uint(v.z)>>16; u.w = __float_as_uint(v.w)>>16;
      *(ushort4*)&Bbf[row][c4] = u;
    }
    __syncthreads();
    #pragma unroll
    for(int kk=0;kk<64;kk+=32){
      bf16x8 a = *(const bf16x8*)&Abf[r0+lm][kk + lg*8];
      #pragma unroll
      for(int f=0;f<4;f++){
        bf16x8 b = *(const bf16x8*)&Bbf[f*16+lm][kk + lg*8];
        acc[f] = __builtin_amdgcn_mfma_f32_16x16x32_bf16(a, b, acc[f], 0,0,0);
      }
    }
    __syncthreads();
  }
  #pragma unroll
  for(int f=0;f<4;f++){
    int gcol = bn*64 + f*16 + lm;
    float eb = e2_b[gcol];
    #pragma unroll
    for(int r=0;r<4;r++){
      int grow = bm*64 + r0 + lg*4 + r;
      size_t o = (size_t)grow*DIN + gcol;
      out[AE_OFF + o] = emb[o] + acc[f][r] + ng[grow]*eb;
    }
  }
  if(bm==0 && bn==0 && t<BSZ) out[SUN_OFF + t] = (float)sun[t];
}

// ---------------- launch ----------------
extern "C" void kernel_launch(void* const* d_in, const int* in_sizes, int n_in,
                              void* d_out, int out_size, void* d_ws, size_t ws_size,
                              hipStream_t stream){
  const float* emb     = (const float*)d_in[0];
  const float* ent     = (const float*)d_in[1];
  const float* key_w   = (const float*)d_in[2];
  const float* key_b   = (const float*)d_in[3];
  const float* q1_w    = (const float*)d_in[4];
  const float* q1_b    = (const float*)d_in[5];
  const float* q2_w    = (const float*)d_in[6];
  const float* q2_b    = (const float*)d_in[7];
  const float* e1_w    = (const float*)d_in[8];
  const float* e1_b    = (const float*)d_in[9];
  const float* e2_w    = (const float*)d_in[10];
  const float* e2_b    = (const float*)d_in[11];
  const float* end_emb = (const float*)d_in[12];
  const float* wih     = (const float*)d_in[13];
  const float* whh     = (const float*)d_in[14];
  const float* ln_ig   = (const float*)d_in[15];
  const float* ln_ib   = (const float*)d_in[16];
  const float* ln_hg   = (const float*)d_in[17];
  const float* ln_hb   = (const float*)d_in[18];
  const float* ln_cg   = (const float*)d_in[19];
  const float* ln_cb   = (const float*)d_in[20];
  const int* en  = (const int*)d_in[21];
  const int* su  = (const int*)d_in[22];
  const int* sun = (const int*)d_in[23];
  float* out = (float*)d_out;
  float* ws  = (float*)d_ws;

  // workspace layout (float units)
  const size_t o_key = 0;                       // 128*513*128 = 8,404,992
  const size_t o_T1  = o_key + 8404992;         // 2,097,152
  const size_t o_q1e = o_T1  + 2097152;         // 65,536
  const size_t o_c0  = o_q1e + 65536;           // 1,024 (256 used)
  const size_t o_U0  = o_c0  + 1024;            // 32,768
  const size_t o_Q1K = o_U0  + 32768;           // 2,097,152
  const size_t o_RU  = o_Q1K + 2097152;         // 2,097,152
  const size_t o_X   = o_RU  + 2097152;         // 1,048,576
  const size_t o_G0  = o_X   + 1048576;         // 4,194,304
  const size_t o_s1  = o_G0  + 4194304;         // 32,768
  const size_t o_ng  = o_s1  + 32768;           // 1,024 (128 used)
  const size_t o_H1  = o_ng  + 1024;            // 1,048,576

  // 1) key = ent @ key_w^T + key_b (MFMA, KEYMAP rows, end-row folded in)
  key_gemm_mfma<<<1024,256,0,stream>>>(ent, key_w, key_b, en, end_emb, ws+o_key);
  // 2) T1 = relu(gather(key,su)/512 @ e1_w^T + e1_b)
  mfma_gemm<false,true,true><<<dim3(128,4),256,0,stream>>>(ws+o_key, e1_w, e1_b, ws+o_T1,
                                                           8192,256,128, su, INV_MAX);
  // 3) q1e = q1_w @ e2_w  (BKMAJOR)
  mfma_gemm<true,false,false><<<dim3(4,4),256,0,stream>>>(q1_w, e2_w, nullptr, ws+o_q1e,
                                                          256,256,1024, nullptr, 1.f);
  // 4) c0 = q1_w @ e2_b
  c0_kernel<<<256,256,0,stream>>>(q1_w, e2_b, ws+o_c0);
  // 5) U0 = emb @ q1_w^T + q1_b
  mfma_gemm<false,false,false><<<dim3(2,4),256,0,stream>>>(emb, q1_w, q1_b, ws+o_U0,
                                                           128,256,1024, nullptr, 1.f);
  // 6) Q1K = T1 @ q1e^T
  mfma_gemm<false,false,false><<<dim3(128,4),256,0,stream>>>(ws+o_T1, ws+o_q1e, nullptr, ws+o_Q1K,
                                                             8192,256,256, nullptr, 1.f);
  // 7) gated exclusive prefix -> relu(U), s1, ng
  prefix_kernel<<<128,256,0,stream>>>(ws+o_U0, ws+o_Q1K, ws+o_c0, ws+o_T1, su, en, sun,
                                      ws+o_RU, ws+o_s1, ws+o_ng);
  // 8) X = RU @ q2_w^T + q2_b
  mfma_gemm<false,false,false><<<dim3(128,2),256,0,stream>>>(ws+o_RU, q2_w, q2_b, ws+o_X,
                                                             8192,128,256, nullptr, 1.f);
  // 9) G0 = LN(X @ wih0^T)  (fused GEMM+LN)
  g0_gemm_ln<<<512,256,0,stream>>>(ws+o_X, wih, ln_ig, ln_ib, ws+o_G0);
  // 10) serial LN-LSTM scan -> H1 (R16 structure: MFMA matvecs, 4 barriers)
  lstm_serial<<<128,512,0,stream>>>(wih, whh, ws+o_G0,
                                    ln_ig, ln_ib, ln_hg, ln_hb, ln_cg, ln_cb, ws+o_H1);
  // 11) logits (masked) directly into d_out
  logits_kernel<<<dim3(128,2),512,0,stream>>>(ws+o_key, ws+o_H1, en, su, out);
  // 12) ae = emb + s1 @ e2_w^T + ng*e2_b ; sun passthrough
  ae_gemm<<<dim3(2,16),256,0,stream>>>(ws+o_s1, e2_w, emb, e2_b, ws+o_ng, sun, out);
}